// Round 1
// baseline (2624.972 us; speedup 1.0000x reference)
//
#include <hip/hip_runtime.h>
#include <math.h>

#define H   512
#define TH3 1536
#define SLEN 96

// ---------------- workspace layout (float offsets) ----------------
// states hT[layer][parity][k=512][b=16]   (transposed: hidden-major)
#define WS_STATE(l,p) ((size_t)((l)*2+(p)) * 8192)
// a1T[parity][512][16]
#define WS_A1(p)      ((size_t)49152 + (size_t)(p)*8192)
// atoms (logits) [t=96][b=16][v=512]
#define WS_ATOMS      ((size_t)65536)
// e buffers [m*16+b][s=96][h=512]  (m=0: e_i (+bb1), m=1: e_j)
#define WS_E          ((size_t)851968)
// total ws use: 2,424,832 floats = ~9.3 MB

__device__ __forceinline__ float sigm_(float x) { return 1.0f / (1.0f + expf(-x)); }

// ---------------- h_init = z @ W_l2h + b_l2h, broadcast to all layers/parities ----
extern "C" __global__ __launch_bounds__(256)
void k_init(const float* __restrict__ z, const float* __restrict__ Wl2h,
            const float* __restrict__ bl2h, float* __restrict__ ws)
{
    const int t  = threadIdx.x;
    const int b  = t & 15, jl = t >> 4;
    const int j  = blockIdx.x * 16 + jl;
    float acc = 0.f;
    #pragma unroll 4
    for (int k = 0; k < H; ++k)
        acc += z[b * H + k] * Wl2h[(size_t)k * H + j];
    acc += bl2h[j];
    #pragma unroll
    for (int l = 0; l < 3; ++l)
        #pragma unroll
        for (int p = 0; p < 2; ++p)
            ws[WS_STATE(l, p) + j * 16 + b] = acc;
}

// ---------------- one pipeline slot ----------------
// jobs by blockIdx>>5: 0=L0(gh only), 1=L1, 2=L2, 3=A1(relu MLP1), 4=LG(logits)
// job j active for s in [j, 95+j].  read parity (s+1)&1, write parity s&1.
extern "C" __global__ __launch_bounds__(512)
void k_slot(const float* __restrict__ W_ih, const float* __restrict__ W_hh,
            const float* __restrict__ b_ih, const float* __restrict__ b_hh,
            const float* __restrict__ Wa1,  const float* __restrict__ ba1,
            const float* __restrict__ Wa2,  const float* __restrict__ ba2,
            float* __restrict__ ws, int s)
{
    __shared__ float lds[8][16][6][17];
    const int bid   = blockIdx.x;
    const int job   = bid >> 5;
    const int jtile = bid & 31;
    if (s < job || s > 95 + job) return;
    const int rp = (s + 1) & 1, wp = s & 1;
    const int tid  = threadIdx.x;
    const int wave = tid >> 6, lane = tid & 63;
    const int jg = lane & 15, bg = lane >> 4;
    const int k0 = wave * 64;

    if (job == 1 || job == 2) {
        const int l = job;
        const float* __restrict__ xT = ws + WS_STATE(l - 1, rp);
        const float* __restrict__ hT = ws + WS_STATE(l,     rp);
        const float* __restrict__ Wi = W_ih + (size_t)l * H * TH3;
        const float* __restrict__ Wh = W_hh + (size_t)l * H * TH3;
        const int j = jtile * 16 + jg;
        float acc[6][4];
        #pragma unroll
        for (int g = 0; g < 6; ++g)
            #pragma unroll
            for (int i = 0; i < 4; ++i) acc[g][i] = 0.f;

        #pragma unroll 4
        for (int k = k0; k < k0 + 64; ++k) {
            float4 xv = *(const float4*)(xT + (size_t)k * 16 + bg * 4);
            float4 hv = *(const float4*)(hT + (size_t)k * 16 + bg * 4);
            const float* wik = Wi + (size_t)k * TH3 + j;
            const float* whk = Wh + (size_t)k * TH3 + j;
            float wir = wik[0], wiz = wik[512], win = wik[1024];
            float whr = whk[0], whz = whk[512], whn = whk[1024];
            acc[0][0] += xv.x * wir; acc[0][1] += xv.y * wir; acc[0][2] += xv.z * wir; acc[0][3] += xv.w * wir;
            acc[1][0] += xv.x * wiz; acc[1][1] += xv.y * wiz; acc[1][2] += xv.z * wiz; acc[1][3] += xv.w * wiz;
            acc[2][0] += xv.x * win; acc[2][1] += xv.y * win; acc[2][2] += xv.z * win; acc[2][3] += xv.w * win;
            acc[3][0] += hv.x * whr; acc[3][1] += hv.y * whr; acc[3][2] += hv.z * whr; acc[3][3] += hv.w * whr;
            acc[4][0] += hv.x * whz; acc[4][1] += hv.y * whz; acc[4][2] += hv.z * whz; acc[4][3] += hv.w * whz;
            acc[5][0] += hv.x * whn; acc[5][1] += hv.y * whn; acc[5][2] += hv.z * whn; acc[5][3] += hv.w * whn;
        }
        #pragma unroll
        for (int g = 0; g < 6; ++g)
            #pragma unroll
            for (int i = 0; i < 4; ++i) lds[wave][jg][g][bg * 4 + i] = acc[g][i];
        __syncthreads();
        if (tid < 256) {
            const int b = tid & 15, jl = tid >> 4;
            const int j2 = jtile * 16 + jl;
            float gs[6];
            #pragma unroll
            for (int g = 0; g < 6; ++g) {
                float v = 0.f;
                #pragma unroll
                for (int w = 0; w < 8; ++w) v += lds[w][jl][g][b];
                gs[g] = v;
            }
            const float* bi = b_ih + l * TH3;
            const float* bh = b_hh + l * TH3;
            float r  = sigm_((gs[0] + bi[j2])        + (gs[3] + bh[j2]));
            float zg = sigm_((gs[1] + bi[512 + j2])  + (gs[4] + bh[512 + j2]));
            float n  = tanhf((gs[2] + bi[1024 + j2]) + r * (gs[5] + bh[1024 + j2]));
            float hp = hT[j2 * 16 + b];
            ws[WS_STATE(l, wp) + j2 * 16 + b] = (1.f - zg) * n + zg * hp;
        }
    } else if (job == 0) {
        // layer 0: x == 0 so gi == b_ih[0]; only the 3 hh dots
        const float* __restrict__ hT = ws + WS_STATE(0, rp);
        const int j = jtile * 16 + jg;
        float acc[3][4];
        #pragma unroll
        for (int g = 0; g < 3; ++g)
            #pragma unroll
            for (int i = 0; i < 4; ++i) acc[g][i] = 0.f;

        #pragma unroll 4
        for (int k = k0; k < k0 + 64; ++k) {
            float4 hv = *(const float4*)(hT + (size_t)k * 16 + bg * 4);
            const float* whk = W_hh + (size_t)k * TH3 + j;   // layer 0
            float whr = whk[0], whz = whk[512], whn = whk[1024];
            acc[0][0] += hv.x * whr; acc[0][1] += hv.y * whr; acc[0][2] += hv.z * whr; acc[0][3] += hv.w * whr;
            acc[1][0] += hv.x * whz; acc[1][1] += hv.y * whz; acc[1][2] += hv.z * whz; acc[1][3] += hv.w * whz;
            acc[2][0] += hv.x * whn; acc[2][1] += hv.y * whn; acc[2][2] += hv.z * whn; acc[2][3] += hv.w * whn;
        }
        #pragma unroll
        for (int g = 0; g < 3; ++g)
            #pragma unroll
            for (int i = 0; i < 4; ++i) lds[wave][jg][g][bg * 4 + i] = acc[g][i];
        __syncthreads();
        if (tid < 256) {
            const int b = tid & 15, jl = tid >> 4;
            const int j2 = jtile * 16 + jl;
            float gs[3];
            #pragma unroll
            for (int g = 0; g < 3; ++g) {
                float v = 0.f;
                #pragma unroll
                for (int w = 0; w < 8; ++w) v += lds[w][jl][g][b];
                gs[g] = v;
            }
            float r  = sigm_(b_ih[j2]          + (gs[0] + b_hh[j2]));
            float zg = sigm_(b_ih[512 + j2]    + (gs[1] + b_hh[512 + j2]));
            float n  = tanhf(b_ih[1024 + j2]   + r * (gs[2] + b_hh[1024 + j2]));
            float hp = hT[j2 * 16 + b];
            ws[WS_STATE(0, wp) + j2 * 16 + b] = (1.f - zg) * n + zg * hp;
        }
    } else {
        // job 3: a1 = relu(h2 @ Wa1 + ba1);  job 4: logits = a1 @ Wa2 + ba2
        const float* __restrict__ xT = (job == 3) ? (ws + WS_STATE(2, rp)) : (ws + WS_A1(rp));
        const float* __restrict__ W  = (job == 3) ? Wa1 : Wa2;
        const int j = jtile * 16 + jg;
        float a0 = 0, a1 = 0, a2 = 0, a3 = 0;
        #pragma unroll 4
        for (int k = k0; k < k0 + 64; ++k) {
            float4 xv = *(const float4*)(xT + (size_t)k * 16 + bg * 4);
            float w = W[(size_t)k * H + j];
            a0 += xv.x * w; a1 += xv.y * w; a2 += xv.z * w; a3 += xv.w * w;
        }
        lds[wave][jg][0][bg * 4 + 0] = a0;
        lds[wave][jg][0][bg * 4 + 1] = a1;
        lds[wave][jg][0][bg * 4 + 2] = a2;
        lds[wave][jg][0][bg * 4 + 3] = a3;
        __syncthreads();
        if (tid < 256) {
            if (job == 3) {
                const int b = tid & 15, jl = tid >> 4;
                const int j2 = jtile * 16 + jl;
                float v = 0.f;
                #pragma unroll
                for (int w = 0; w < 8; ++w) v += lds[w][jl][0][b];
                v += ba1[j2];
                ws[WS_A1(wp) + j2 * 16 + b] = fmaxf(v, 0.f);
            } else {
                const int jl = tid & 15, b = tid >> 4;   // jl fast for coalesced atoms write
                const int j2 = jtile * 16 + jl;
                float v = 0.f;
                #pragma unroll
                for (int w = 0; w < 8; ++w) v += lds[w][jl][0][b];
                v += ba2[j2];
                const int t_ = s - 4;
                ws[WS_ATOMS + ((size_t)t_ * 16 + b) * H + j2] = v;
            }
        }
    }
}

// ---------------- argmax over logits (first-max-wins, numpy semantics) ----------
extern "C" __global__ __launch_bounds__(256)
void k_argmax(const float* __restrict__ ws, float* __restrict__ out)
{
    const int t = blockIdx.x;                  // 0..95
    const int wv = threadIdx.x >> 6, lane = threadIdx.x & 63;
    for (int b = wv; b < 16; b += 4) {
        const float* row = ws + WS_ATOMS + ((size_t)t * 16 + b) * H;
        float mx = -3.4028235e38f; int mi = 0;
        #pragma unroll
        for (int c = 0; c < 8; ++c) {
            int idx = lane + c * 64;
            float v = row[idx];
            if (v > mx) { mx = v; mi = idx; }
        }
        #pragma unroll
        for (int off = 32; off >= 1; off >>= 1) {
            float omx = __shfl_down(mx, off);
            int   omi = __shfl_down(mi, off);
            if (omx > mx || (omx == mx && omi < mi)) { mx = omx; mi = omi; }
        }
        if (lane == 0) out[b * 96 + t] = (float)mi;
    }
}

// ---------------- e_i / e_j = atoms @ Wb1 halves (+ bb1 folded into e_i) -------
extern "C" __global__ __launch_bounds__(128)
void k_eij(const float* __restrict__ Wb1, const float* __restrict__ bb1,
           float* __restrict__ ws)
{
    const int gb = blockIdx.x;                 // 0..3071
    const int m = gb / 1536, row = gb % 1536;  // row = t*16 + b
    const int sI = row >> 4, b = row & 15;
    const float* __restrict__ arow = ws + WS_ATOMS + (size_t)row * H;
    const float* __restrict__ W    = Wb1 + (size_t)m * H * H;
    const int h0 = threadIdx.x * 4;
    float a0 = 0, a1 = 0, a2 = 0, a3 = 0;
    #pragma unroll 4
    for (int k = 0; k < H; ++k) {
        float a = arow[k];                     // uniform across block -> scalar load
        float4 w = *(const float4*)(W + (size_t)k * H + h0);
        a0 += a * w.x; a1 += a * w.y; a2 += a * w.z; a3 += a * w.w;
    }
    if (m == 0) { a0 += bb1[h0]; a1 += bb1[h0 + 1]; a2 += bb1[h0 + 2]; a3 += bb1[h0 + 3]; }
    float4 o; o.x = a0; o.y = a1; o.z = a2; o.w = a3;
    *(float4*)(ws + WS_E + ((size_t)(m * 16 + b) * 96 + sI) * H + h0) = o;
}

// ---------------- fused edge MLP: relu(e_i + e_j) @ Wb2 + bb2, diag zeroed -----
extern "C" __global__ __launch_bounds__(256)
void k_edge(const float* __restrict__ Wb2, const float* __restrict__ bb2,
            const float* __restrict__ ws, float* __restrict__ out)
{
    __shared__ float ls[32][260];              // 16 e_i rows + 16 e_j rows, padded
    const int bid = blockIdx.x;                // b*36 + it*6 + jt
    const int b = bid / 36, r6 = bid % 36, it = r6 / 6, jt = r6 % 6;
    const int tid = threadIdx.x;
    const int ip = tid & 15, jp = tid >> 4;
    float acc0 = 0, acc1 = 0, acc2 = 0, acc3 = 0;

    for (int ph = 0; ph < 2; ++ph) {
        __syncthreads();
        for (int f = tid; f < 2048; f += 256) {
            int r = f >> 6, c4 = f & 63;
            const float* src = (r < 16)
                ? ws + WS_E + ((size_t)b * 96 + it * 16 + r) * H
                : ws + WS_E + ((size_t)(16 + b) * 96 + jt * 16 + (r - 16)) * H;
            float4 v = *(const float4*)(src + ph * 256 + c4 * 4);
            *(float4*)&ls[r][c4 * 4] = v;
        }
        __syncthreads();
        const float* wb = Wb2 + (size_t)ph * 256 * 4;
        #pragma unroll 2
        for (int hh = 0; hh < 256; hh += 4) {
            float4 ei = *(const float4*)&ls[ip][hh];
            float4 ej = *(const float4*)&ls[16 + jp][hh];
            const float* w = wb + (size_t)hh * 4;    // uniform -> scalar loads
            float v;
            v = fmaxf(ei.x + ej.x, 0.f); acc0 += v * w[0];  acc1 += v * w[1];  acc2 += v * w[2];  acc3 += v * w[3];
            v = fmaxf(ei.y + ej.y, 0.f); acc0 += v * w[4];  acc1 += v * w[5];  acc2 += v * w[6];  acc3 += v * w[7];
            v = fmaxf(ei.z + ej.z, 0.f); acc0 += v * w[8];  acc1 += v * w[9];  acc2 += v * w[10]; acc3 += v * w[11];
            v = fmaxf(ei.w + ej.w, 0.f); acc0 += v * w[12]; acc1 += v * w[13]; acc2 += v * w[14]; acc3 += v * w[15];
        }
    }
    const int i = it * 16 + ip, j = jt * 16 + jp;
    float4 o;
    if (i == j) { o.x = 0.f; o.y = 0.f; o.z = 0.f; o.w = 0.f; }
    else { o.x = acc0 + bb2[0]; o.y = acc1 + bb2[1]; o.z = acc2 + bb2[2]; o.w = acc3 + bb2[3]; }
    *(float4*)(out + 1536 + (((size_t)b * 96 + i) * 96 + j) * 4) = o;
}

// ---------------- host ----------------
extern "C" void kernel_launch(void* const* d_in, const int* in_sizes, int n_in,
                              void* d_out, int out_size, void* d_ws, size_t ws_size,
                              hipStream_t stream)
{
    const float* z    = (const float*)d_in[0];
    const float* Wl2h = (const float*)d_in[1];
    const float* bl2h = (const float*)d_in[2];
    const float* W_ih = (const float*)d_in[3];
    const float* W_hh = (const float*)d_in[4];
    const float* b_ih = (const float*)d_in[5];
    const float* b_hh = (const float*)d_in[6];
    const float* Wa1  = (const float*)d_in[7];
    const float* ba1  = (const float*)d_in[8];
    const float* Wa2  = (const float*)d_in[9];
    const float* ba2  = (const float*)d_in[10];
    const float* Wb1  = (const float*)d_in[11];
    const float* bb1  = (const float*)d_in[12];
    const float* Wb2  = (const float*)d_in[13];
    const float* bb2  = (const float*)d_in[14];
    float* out = (float*)d_out;
    float* ws  = (float*)d_ws;

    hipLaunchKernelGGL(k_init, dim3(32), dim3(256), 0, stream, z, Wl2h, bl2h, ws);
    for (int s = 0; s < 100; ++s)
        hipLaunchKernelGGL(k_slot, dim3(160), dim3(512), 0, stream,
                           W_ih, W_hh, b_ih, b_hh, Wa1, ba1, Wa2, ba2, ws, s);
    hipLaunchKernelGGL(k_argmax, dim3(96), dim3(256), 0, stream, ws, out);
    hipLaunchKernelGGL(k_eij, dim3(3072), dim3(128), 0, stream, Wb1, bb1, ws);
    hipLaunchKernelGGL(k_edge, dim3(576), dim3(256), 0, stream, Wb2, bb2, ws, out);
}